// Round 3
// baseline (1909.282 us; speedup 1.0000x reference)
//
#include <hip/hip_runtime.h>
#include <hip/hip_bf16.h>

// Shapes: B=512, S=128, D=128, HS=256, 4HS=1024, O=1.
// k_seq v3: 64 blocks = 32 batch-groups x 2 half-blocks. Each half-block owns
// k-slice [hf*128, hf*128+128) of all 4 gates (512 cols). U slice is FULLY
// register-resident (128 VGPRs/wave). Per step the two halves exchange their
// h(t+1) halves (4KB raw [row][k] bf16) + y partials through L2 using
// t-indexed slots + monotonic device-scope flags (no slot reuse).

using bf16x8 = __attribute__((ext_vector_type(8))) short;
using f32x4  = __attribute__((ext_vector_type(4))) float;

#define DEV static __device__ __forceinline__

DEV unsigned short f2bf(float x) {
    unsigned u = __float_as_uint(x);
    u += 0x7fffu + ((u >> 16) & 1u);          // round-to-nearest-even
    return (unsigned short)(u >> 16);
}
DEV float bf2f(unsigned short s) { return __uint_as_float(((unsigned)s) << 16); }
DEV float sigm(float x) { return 1.0f / (1.0f + __expf(-x)); }
DEV float tanh_f(float x) { float e = __expf(2.0f * x); return 1.0f - 2.0f / (e + 1.0f); }
DEV f32x4 mfma16(bf16x8 a, bf16x8 b, f32x4 c) {
    return __builtin_amdgcn_mfma_f32_16x16x32_bf16(a, b, c, 0, 0, 0);
}

// stage rows x 128 bf16 (row stride 128) into LDS with padded stride 136
DEV void stage128(const unsigned short* __restrict__ src, unsigned short* dst, int rows, int tid) {
    int chunks = rows * 16;
    for (int i = tid; i < chunks; i += 256) {
        int r = i >> 4, c = (i & 15) << 3;
        *(bf16x8*)(dst + r * 136 + c) = *(const bf16x8*)(src + r * 128 + c);
    }
}

// ---------------- prep kernels ----------------
__global__ void k_prepw(const float* __restrict__ Wa, const float* __restrict__ Va,
                        const float* __restrict__ W, const float* __restrict__ U,
                        unsigned short* __restrict__ WaT, unsigned short* __restrict__ VaT,
                        unsigned short* __restrict__ WT, unsigned short* __restrict__ Upk,
                        unsigned int* __restrict__ flags) {
    int idx = blockIdx.x * 256 + threadIdx.x;
    if (idx < 16384) {
        int n = idx >> 7, k = idx & 127;
        WaT[idx] = f2bf(Wa[k * 128 + n]);
    } else if (idx < 32768) {
        int i = idx - 16384;
        int n = i >> 7, k = i & 127;
        VaT[i] = f2bf(Va[k * 128 + n]);
    } else if (idx < 163840) {
        int i = idx - 32768;
        int n = i >> 7, k = i & 127;
        WT[i] = f2bf(W[k * 1024 + n]);
    } else if (idx < 425984) {
        int i = idx - 163840;   // layout: (((((hf*8+w)*4+gate)*8+kc)*64+l)*8+j
        int j = i & 7, l = (i >> 3) & 63, kc = (i >> 9) & 7, gate = (i >> 12) & 3,
            w = (i >> 14) & 7, hf = (i >> 17) & 1;
        int k = kc * 32 + (l >> 4) * 8 + j;
        int n = gate * 256 + hf * 128 + w * 16 + (l & 15);
        Upk[i] = f2bf(U[k * 1024 + n]);
    } else if (idx < 426048) {
        flags[idx - 425984] = 0u;   // zero exchange flags (re-poisoned ws each launch)
    }
}

__global__ void k_preph(const float* __restrict__ H, unsigned short* __restrict__ Hbf,
                        unsigned short* __restrict__ HT) {
    for (size_t idx = (size_t)blockIdx.x * 256 + threadIdx.x; idx < 16777216u;
         idx += (size_t)gridDim.x * 256) {
        if (idx < 8388608u) {
            Hbf[idx] = f2bf(H[idx]);
        } else {
            size_t i = idx - 8388608u;
            int b = (int)(i >> 14);
            int rem = (int)(i & 16383);
            int d = rem >> 7, s = rem & 127;
            HT[i] = f2bf(H[((size_t)b * 128 + s) * 128 + d]);
        }
    }
}

// ---------------- T1 = tanh(H @ Wa + ba) ----------------
__global__ __launch_bounds__(256) void k_att1(const unsigned short* __restrict__ Hbf,
                                              const unsigned short* __restrict__ WaT,
                                              const float* __restrict__ ba,
                                              unsigned short* __restrict__ T1) {
    __shared__ unsigned short a_lds[64 * 136];
    __shared__ unsigned short b_lds[128 * 136];
    int tid = threadIdx.x;
    int m0 = blockIdx.x * 64;
    stage128(Hbf + (size_t)m0 * 128, a_lds, 64, tid);
    stage128(WaT, b_lds, 128, tid);
    __syncthreads();
    int w = tid >> 6, l = tid & 63, q = l >> 4, r = l & 15;
    f32x4 acc[8] = {};
    #pragma unroll
    for (int kc = 0; kc < 4; ++kc) {
        bf16x8 a = *(const bf16x8*)(a_lds + (w * 16 + r) * 136 + kc * 32 + q * 8);
        #pragma unroll
        for (int nt = 0; nt < 8; ++nt) {
            bf16x8 b = *(const bf16x8*)(b_lds + (nt * 16 + r) * 136 + kc * 32 + q * 8);
            acc[nt] = mfma16(a, b, acc[nt]);
        }
    }
    #pragma unroll
    for (int nt = 0; nt < 8; ++nt) {
        int col = nt * 16 + r;
        float bav = ba[col];
        #pragma unroll
        for (int j = 0; j < 4; ++j) {
            int row = m0 + w * 16 + q * 4 + j;
            T1[(size_t)row * 128 + col] = f2bf(tanh_f(acc[nt][j] + bav));
        }
    }
}

// ---------------- beta = softmax(T1 @ Va) ----------------
__global__ __launch_bounds__(256) void k_att2(const unsigned short* __restrict__ T1,
                                              const unsigned short* __restrict__ VaT,
                                              unsigned short* __restrict__ beta) {
    __shared__ __align__(16) char smem[52224];
    unsigned short* a_lds = (unsigned short*)smem;
    unsigned short* b_lds = (unsigned short*)(smem + 17408);
    float* lg  = (float*)smem;
    float* inv = (float*)(smem + 34048);
    int tid = threadIdx.x;
    int m0 = blockIdx.x * 64;
    stage128(T1 + (size_t)m0 * 128, a_lds, 64, tid);
    stage128(VaT, b_lds, 128, tid);
    __syncthreads();
    int w = tid >> 6, l = tid & 63, q = l >> 4, r = l & 15;
    f32x4 acc[8] = {};
    #pragma unroll
    for (int kc = 0; kc < 4; ++kc) {
        bf16x8 a = *(const bf16x8*)(a_lds + (w * 16 + r) * 136 + kc * 32 + q * 8);
        #pragma unroll
        for (int nt = 0; nt < 8; ++nt) {
            bf16x8 b = *(const bf16x8*)(b_lds + (nt * 16 + r) * 136 + kc * 32 + q * 8);
            acc[nt] = mfma16(a, b, acc[nt]);
        }
    }
    __syncthreads();
    #pragma unroll
    for (int nt = 0; nt < 8; ++nt)
        #pragma unroll
        for (int j = 0; j < 4; ++j)
            lg[(w * 16 + q * 4 + j) * 133 + nt * 16 + r] = acc[nt][j];
    __syncthreads();
    if (tid < 64) {
        float mx = -1e30f;
        for (int c = 0; c < 128; ++c) mx = fmaxf(mx, lg[tid * 133 + c]);
        float s = 0.f;
        for (int c = 0; c < 128; ++c) {
            float e = __expf(lg[tid * 133 + c] - mx);
            lg[tid * 133 + c] = e;
            s += e;
        }
        inv[tid] = 1.0f / s;
    }
    __syncthreads();
    for (int i = tid; i < 64 * 128; i += 256) {
        int rr = i >> 7, cc = i & 127;
        beta[(size_t)(m0 + rr) * 128 + cc] = f2bf(lg[rr * 133 + cc] * inv[rr]);
    }
}

// ---------------- poolT[t*512+b][d] = beta[b] @ H[b] ----------------
__global__ __launch_bounds__(256) void k_pool(const unsigned short* __restrict__ beta,
                                              const unsigned short* __restrict__ HT,
                                              unsigned short* __restrict__ poolT) {
    __shared__ unsigned short a_lds[64 * 136];
    __shared__ unsigned short b_lds[128 * 136];
    int tid = threadIdx.x;
    int b = blockIdx.x >> 1, mh = blockIdx.x & 1;
    stage128(beta + ((size_t)b * 128 + mh * 64) * 128, a_lds, 64, tid);
    stage128(HT + (size_t)b * 16384, b_lds, 128, tid);
    __syncthreads();
    int w = tid >> 6, l = tid & 63, q = l >> 4, r = l & 15;
    f32x4 acc[8] = {};
    #pragma unroll
    for (int kc = 0; kc < 4; ++kc) {
        bf16x8 a = *(const bf16x8*)(a_lds + (w * 16 + r) * 136 + kc * 32 + q * 8);
        #pragma unroll
        for (int nt = 0; nt < 8; ++nt) {
            bf16x8 bb = *(const bf16x8*)(b_lds + (nt * 16 + r) * 136 + kc * 32 + q * 8);
            acc[nt] = mfma16(a, bb, acc[nt]);
        }
    }
    #pragma unroll
    for (int nt = 0; nt < 8; ++nt)
        #pragma unroll
        for (int j = 0; j < 4; ++j) {
            int t = mh * 64 + w * 16 + q * 4 + j;
            poolT[((size_t)t * 512 + b) * 128 + nt * 16 + r] = f2bf(acc[nt][j]);
        }
}

// ---------------- Gx = pool @ W + bias, packed for k_seq v3 ----------------
// Gxp layout (shorts): ((((g*128+t)*2+hf)*8+w)*2+pair)*512 + l*8 + (gate&1)*4 + j
__global__ __launch_bounds__(256) void k_gx(const unsigned short* __restrict__ poolT,
                                            const unsigned short* __restrict__ WT,
                                            const float* __restrict__ bias,
                                            unsigned short* __restrict__ Gxp) {
    __shared__ unsigned short a_lds[64 * 136];
    __shared__ unsigned short b_lds[128 * 136];
    int tid = threadIdx.x;
    int mblk = blockIdx.x >> 3, nb = blockIdx.x & 7;
    int t = mblk >> 3;
    int m0 = mblk * 64, n0 = nb * 128;
    stage128(poolT + (size_t)m0 * 128, a_lds, 64, tid);
    stage128(WT + (size_t)n0 * 128, b_lds, 128, tid);
    __syncthreads();
    int w = tid >> 6, l = tid & 63, q = l >> 4, r = l & 15;
    f32x4 acc[8] = {};
    #pragma unroll
    for (int kc = 0; kc < 4; ++kc) {
        bf16x8 a = *(const bf16x8*)(a_lds + (w * 16 + r) * 136 + kc * 32 + q * 8);
        #pragma unroll
        for (int nt = 0; nt < 8; ++nt) {
            bf16x8 bb = *(const bf16x8*)(b_lds + (nt * 16 + r) * 136 + kc * 32 + q * 8);
            acc[nt] = mfma16(a, bb, acc[nt]);
        }
    }
    int g_seq = (mblk & 7) * 4 + w;   // wave's 16 rows = one sequential batch group
    #pragma unroll
    for (int nt = 0; nt < 8; ++nt) {
        int col0 = n0 + nt * 16;
        float bv = bias[col0 + r];
        int gate = col0 >> 8;
        int hf = (col0 >> 7) & 1;
        int w_seq = (col0 >> 4) & 7;
        int pair = gate >> 1, lo = gate & 1;
        size_t s16 = ((((size_t)g_seq * 128 + t) * 2 + hf) * 8 + w_seq) * 2 + pair;
        ushort4 o;
        o.x = f2bf(acc[nt][0] + bv);
        o.y = f2bf(acc[nt][1] + bv);
        o.z = f2bf(acc[nt][2] + bv);
        o.w = f2bf(acc[nt][3] + bv);
        *(ushort4*)(Gxp + s16 * 512 + (size_t)l * 8 + lo * 4) = o;
    }
}

// ---------------- sequential LSTM: 64 blocks = 32 groups x 2 halves ----------------
// hx slot (per block, per t): 2112 shorts = raw h-half [16 rows][128 k] bf16 (2048)
//                             + 16 f32 y-partials (32 shorts) + pad
__global__ __launch_bounds__(512, 1) void k_seq(const unsigned short* __restrict__ Gxp,
                                                const unsigned short* __restrict__ Upk,
                                                const float* __restrict__ Wy,
                                                const float* __restrict__ fcW,
                                                const float* __restrict__ fcb,
                                                const float* __restrict__ y0,
                                                unsigned short* __restrict__ hx,
                                                unsigned int* __restrict__ flags,
                                                float* __restrict__ out) {
    __shared__ unsigned short h_own[2][2048];          // own half h, A-frag order, dbuf
    __shared__ __align__(16) float ypart[2][16][8];    // [parity][row][wave]

    int tid = threadIdx.x;
    int bx = blockIdx.x;
    int g = bx >> 1, hf = bx & 1;
    int w = tid >> 6, l = tid & 63, q = l >> 4, r = l & 15;
    float fcb0 = fcb[0];

    // fully register-resident U slice: [gate][kc_abs] (128 VGPRs)
    bf16x8 u_res[4][8];
    #pragma unroll
    for (int gate = 0; gate < 4; ++gate)
        #pragma unroll
        for (int kc = 0; kc < 8; ++kc)
            u_res[gate][kc] = *(const bf16x8*)(
                Upk + ((size_t)((((hf * 8 + w) * 4 + gate) * 8 + kc) * 64 + l)) * 8);

    int kk = hf * 128 + w * 16 + r;     // this lane's owned h index
    float wyv[4];
    #pragma unroll
    for (int gate = 0; gate < 4; ++gate) wyv[gate] = Wy[gate * 256 + kk];
    float fw = fcW[kk];
    float c_st[4] = {0.f, 0.f, 0.f, 0.f};

    volatile unsigned int* pflag = flags + (bx ^ 1);
    unsigned int* myflag = flags + bx;

    float* outh = out + 512;
    for (int t = 0; t < 128; ++t) {
        int par = t & 1, npar = par ^ 1;

        // Gx (independent of partner) issued first
        size_t gbase = ((((size_t)g * 128 + t) * 2 + hf) * 8 + w) * 2;
        const bf16x8* gq = (const bf16x8*)Gxp;
        bf16x8 gx0 = gq[gbase * 64 + l];
        bf16x8 gx1 = gq[(gbase + 1) * 64 + l];

        bf16x8 ap[4];   // partner-half A frags (from L2)
        bf16x8 ao[4];   // own-half A frags (from LDS)
        float yprev[4];
        if (t) {
            if (l == 0) {
                while (__hip_atomic_load((const unsigned int*)pflag, __ATOMIC_ACQUIRE,
                                         __HIP_MEMORY_SCOPE_AGENT) < (unsigned)t)
                    __builtin_amdgcn_s_sleep(1);
            }
            __builtin_amdgcn_wave_barrier();
            const unsigned short* ps = hx + ((size_t)(bx ^ 1) * 128 + (t - 1)) * 2112;
            #pragma unroll
            for (int kcp = 0; kcp < 4; ++kcp)
                ap[kcp] = *(const bf16x8*)(ps + r * 128 + kcp * 32 + q * 8);
            #pragma unroll
            for (int kcp = 0; kcp < 4; ++kcp)
                ao[kcp] = *(const bf16x8*)(&h_own[par][0] + ((kcp * 4 + q) * 16 + r) * 8);
            const float* py = (const float*)(ps + 2048);
            #pragma unroll
            for (int j = 0; j < 4; ++j) {
                int row = q * 4 + j;
                float4 p0 = *(const float4*)&ypart[par][row][0];
                float4 p1 = *(const float4*)&ypart[par][row][4];
                yprev[j] = fcb0 + p0.x + p0.y + p0.z + p0.w + p1.x + p1.y + p1.z + p1.w
                         + py[row];
            }
        } else {
            #pragma unroll
            for (int j = 0; j < 4; ++j) yprev[j] = y0[g * 16 + q * 4 + j];
        }

        f32x4 acc[4];
        #pragma unroll
        for (int gate = 0; gate < 4; ++gate) {
            acc[gate][0] = yprev[0] * wyv[gate];
            acc[gate][1] = yprev[1] * wyv[gate];
            acc[gate][2] = yprev[2] * wyv[gate];
            acc[gate][3] = yprev[3] * wyv[gate];
        }
        if (t) {
            #pragma unroll
            for (int kc = 0; kc < 8; ++kc) {
                bf16x8 a = ((kc >> 2) == hf) ? ao[kc & 3] : ap[kc & 3];
                #pragma unroll
                for (int gate = 0; gate < 4; ++gate)
                    acc[gate] = mfma16(a, u_res[gate][kc], acc[gate]);
            }
        }

        // ---- LSTM cell (this lane: 4 rows x 1 k) ----
        unsigned short* ms = hx + ((size_t)bx * 128 + t) * 2112;
        float ypj[4];
        #pragma unroll
        for (int j = 0; j < 4; ++j) {
            int row = q * 4 + j;
            float iv = sigm(acc[0][j] + bf2f((unsigned short)gx0[j]));
            float fv = sigm(acc[1][j] + bf2f((unsigned short)gx0[4 + j]));
            float gv = tanh_f(acc[2][j] + bf2f((unsigned short)gx1[j]));
            float ov = sigm(acc[3][j] + bf2f((unsigned short)gx1[4 + j]));
            float c = fv * c_st[j] + iv * gv;
            c_st[j] = c;
            float hv = ov * tanh_f(c);
            unsigned short hb = f2bf(hv);
            outh[((size_t)(g * 16 + row) * 128 + t) * 256 + kk] = hv;
            ms[row * 128 + w * 16 + r] = hb;                       // raw half for partner
            h_own[npar][((w * 2 + (r >> 3)) * 16 + row) * 8 + (r & 7)] = hb;  // frag order
            ypj[j] = hv * fw;
        }
        #pragma unroll
        for (int j = 0; j < 4; ++j) {   // reduce over the 16 r-lanes
            float v = ypj[j];
            v += __shfl_xor(v, 1);
            v += __shfl_xor(v, 2);
            v += __shfl_xor(v, 4);
            v += __shfl_xor(v, 8);
            if (r == 0) ypart[npar][q * 4 + j][w] = v;
        }
        __syncthreads();   // drains each wave's global h stores (vmcnt(0) pre-barrier)
        if (tid < 16) {    // wave 0 publishes y partial + flag
            float s = 0.f;
            float4 p0 = *(const float4*)&ypart[npar][tid][0];
            float4 p1 = *(const float4*)&ypart[npar][tid][4];
            s = p0.x + p0.y + p0.z + p0.w + p1.x + p1.y + p1.z + p1.w;
            ((float*)(ms + 2048))[tid] = s;
        }
        if (tid == 0) {
            __threadfence();   // wave0's y store drained (vmcnt is per-wave)
            __hip_atomic_store(myflag, (unsigned)(t + 1), __ATOMIC_RELEASE,
                               __HIP_MEMORY_SCOPE_AGENT);
        }
    }

    // final y = y(128): written by hf==0 block only
    if (hf == 0) {
        if (tid == 0) {
            while (__hip_atomic_load(flags + (bx ^ 1), __ATOMIC_ACQUIRE,
                                     __HIP_MEMORY_SCOPE_AGENT) < 128u)
                __builtin_amdgcn_s_sleep(1);
        }
        __builtin_amdgcn_wave_barrier();
        if (tid < 16) {
            const unsigned short* ps = hx + ((size_t)(bx ^ 1) * 128 + 127) * 2112;
            float pv = ((const float*)(ps + 2048))[tid];
            float own = 0.f;
            #pragma unroll
            for (int ww = 0; ww < 8; ++ww) own += ypart[0][tid][ww];
            out[g * 16 + tid] = fcb0 + own + pv;
        }
    }
}

extern "C" void kernel_launch(void* const* d_in, const int* in_sizes, int n_in,
                              void* d_out, int out_size, void* d_ws, size_t ws_size,
                              hipStream_t stream) {
    const float* H    = (const float*)d_in[0];
    const float* y0   = (const float*)d_in[1];
    const float* Wa   = (const float*)d_in[2];
    // d_in[3] = Ua: multiplied by an all-zero state in the reference -> unused
    const float* ba   = (const float*)d_in[4];
    const float* Va   = (const float*)d_in[5];
    const float* W    = (const float*)d_in[6];
    const float* U    = (const float*)d_in[7];
    const float* bias = (const float*)d_in[8];
    const float* Wy   = (const float*)d_in[9];
    const float* fcW  = (const float*)d_in[10];
    const float* fcb  = (const float*)d_in[11];
    float* out = (float*)d_out;
    char* ws = (char*)d_ws;

    unsigned short* Hbf   = (unsigned short*)(ws);                       // 16.78 MB
    unsigned short* HT    = (unsigned short*)(ws + 16777216);            // 16.78 MB
    unsigned short* T1    = (unsigned short*)(ws + 2 * 16777216);        // 16.78 MB
    unsigned short* beta  = (unsigned short*)(ws + 3 * 16777216);        // 16.78 MB
    unsigned short* poolT = (unsigned short*)(ws + 4 * 16777216);        // 16.78 MB
    unsigned short* Gxp   = (unsigned short*)(ws + (size_t)5 * 16777216);        // 134.2 MB
    unsigned short* WaT   = (unsigned short*)(ws + (size_t)5 * 16777216 + 134217728);
    unsigned short* VaT   = WaT + 16384;
    unsigned short* WT    = VaT + 16384;
    unsigned short* Upk   = WT + 131072;
    unsigned int*   flags = (unsigned int*)(Upk + 262144);
    // hx (34.6 MB) overlaps HT+T1+1MB of beta -- all dead before k_seq runs
    unsigned short* hx    = HT;

    hipLaunchKernelGGL(k_prepw, dim3(1665), dim3(256), 0, stream, Wa, Va, W, U,
                       WaT, VaT, WT, Upk, flags);
    hipLaunchKernelGGL(k_preph, dim3(8192), dim3(256), 0, stream, H, Hbf, HT);
    hipLaunchKernelGGL(k_att1, dim3(1024), dim3(256), 0, stream, Hbf, WaT, ba, T1);
    hipLaunchKernelGGL(k_att2, dim3(1024), dim3(256), 0, stream, T1, VaT, beta);
    hipLaunchKernelGGL(k_pool, dim3(1024), dim3(256), 0, stream, beta, HT, poolT);
    hipLaunchKernelGGL(k_gx, dim3(8192), dim3(256), 0, stream, poolT, WT, bias, Gxp);
    hipLaunchKernelGGL(k_seq, dim3(64), dim3(512), 0, stream, Gxp, Upk, Wy, fcW, fcb,
                       y0, hx, flags, out);
}

// Round 4
// 1443.159 us; speedup vs baseline: 1.3230x; 1.3230x over previous
//
#include <hip/hip_runtime.h>
#include <hip/hip_bf16.h>

// Shapes: B=512, S=128, D=128, HS=256, 4HS=1024, O=1.
// k_seq v4: 128 blocks = 32 batch-groups x 4 k-quarter blocks, 256 threads.
// Each block owns k-slice [qf*64, qf*64+64) of all 4 gates; its U slice
// (256x256 bf16 = 128 KB) is LDS-resident, loaded once. Per step: 4 waves x
// (8 A-frags, 32 ds_read_b128 B-frags, 32 MFMA), cell, then publish h quarter
// (A-frag order) + y partial via relaxed agent-scope (sc1, L3-coherent)
// atomics into t-indexed slots; monotonic flags; NO release fences (no
// buffer_wbl2 — that was the r3 killer); one acquire fence (buffer_inv) per
// step on the reader side.

using bf16x8 = __attribute__((ext_vector_type(8))) short;
using f32x4  = __attribute__((ext_vector_type(4))) float;

#define DEV static __device__ __forceinline__

DEV unsigned short f2bf(float x) {
    unsigned u = __float_as_uint(x);
    u += 0x7fffu + ((u >> 16) & 1u);          // round-to-nearest-even
    return (unsigned short)(u >> 16);
}
DEV float bf2f(unsigned short s) { return __uint_as_float(((unsigned)s) << 16); }
DEV float sigm(float x) { return 1.0f / (1.0f + __expf(-x)); }
DEV float tanh_f(float x) { float e = __expf(2.0f * x); return 1.0f - 2.0f / (e + 1.0f); }
DEV f32x4 mfma16(bf16x8 a, bf16x8 b, f32x4 c) {
    return __builtin_amdgcn_mfma_f32_16x16x32_bf16(a, b, c, 0, 0, 0);
}

// stage rows x 128 bf16 (row stride 128) into LDS with padded stride 136
DEV void stage128(const unsigned short* __restrict__ src, unsigned short* dst, int rows, int tid) {
    int chunks = rows * 16;
    for (int i = tid; i < chunks; i += 256) {
        int r = i >> 4, c = (i & 15) << 3;
        *(bf16x8*)(dst + r * 136 + c) = *(const bf16x8*)(src + r * 128 + c);
    }
}

// ---------------- prep kernels ----------------
__global__ void k_prepw(const float* __restrict__ Wa, const float* __restrict__ Va,
                        const float* __restrict__ W, const float* __restrict__ U,
                        unsigned short* __restrict__ WaT, unsigned short* __restrict__ VaT,
                        unsigned short* __restrict__ WT, unsigned short* __restrict__ Upk,
                        unsigned int* __restrict__ flags) {
    int idx = blockIdx.x * 256 + threadIdx.x;
    if (idx < 16384) {
        int n = idx >> 7, k = idx & 127;
        WaT[idx] = f2bf(Wa[k * 128 + n]);
    } else if (idx < 32768) {
        int i = idx - 16384;
        int n = i >> 7, k = i & 127;
        VaT[i] = f2bf(Va[k * 128 + n]);
    } else if (idx < 163840) {
        int i = idx - 32768;
        int n = i >> 7, k = i & 127;
        WT[i] = f2bf(W[k * 1024 + n]);
    } else if (idx < 425984) {
        int i = idx - 163840;   // layout: [qf][c][gate][kc][l][j]
        int j = i & 7, l = (i >> 3) & 63, kc = (i >> 9) & 7, gate = (i >> 12) & 3,
            c = (i >> 14) & 3, qf = (i >> 16) & 3;
        int k = kc * 32 + (l >> 4) * 8 + j;
        int n = gate * 256 + qf * 64 + c * 16 + (l & 15);
        Upk[i] = f2bf(U[k * 1024 + n]);
    } else if (idx < 426496) {
        flags[idx - 425984] = 0u;   // zero exchange flags (ws re-poisoned each launch)
    }
}

__global__ void k_preph(const float* __restrict__ H, unsigned short* __restrict__ Hbf,
                        unsigned short* __restrict__ HT) {
    for (size_t idx = (size_t)blockIdx.x * 256 + threadIdx.x; idx < 16777216u;
         idx += (size_t)gridDim.x * 256) {
        if (idx < 8388608u) {
            Hbf[idx] = f2bf(H[idx]);
        } else {
            size_t i = idx - 8388608u;
            int b = (int)(i >> 14);
            int rem = (int)(i & 16383);
            int d = rem >> 7, s = rem & 127;
            HT[i] = f2bf(H[((size_t)b * 128 + s) * 128 + d]);
        }
    }
}

// ---------------- T1 = tanh(H @ Wa + ba) ----------------
__global__ __launch_bounds__(256) void k_att1(const unsigned short* __restrict__ Hbf,
                                              const unsigned short* __restrict__ WaT,
                                              const float* __restrict__ ba,
                                              unsigned short* __restrict__ T1) {
    __shared__ unsigned short a_lds[64 * 136];
    __shared__ unsigned short b_lds[128 * 136];
    int tid = threadIdx.x;
    int m0 = blockIdx.x * 64;
    stage128(Hbf + (size_t)m0 * 128, a_lds, 64, tid);
    stage128(WaT, b_lds, 128, tid);
    __syncthreads();
    int w = tid >> 6, l = tid & 63, q = l >> 4, r = l & 15;
    f32x4 acc[8] = {};
    #pragma unroll
    for (int kc = 0; kc < 4; ++kc) {
        bf16x8 a = *(const bf16x8*)(a_lds + (w * 16 + r) * 136 + kc * 32 + q * 8);
        #pragma unroll
        for (int nt = 0; nt < 8; ++nt) {
            bf16x8 b = *(const bf16x8*)(b_lds + (nt * 16 + r) * 136 + kc * 32 + q * 8);
            acc[nt] = mfma16(a, b, acc[nt]);
        }
    }
    #pragma unroll
    for (int nt = 0; nt < 8; ++nt) {
        int col = nt * 16 + r;
        float bav = ba[col];
        #pragma unroll
        for (int j = 0; j < 4; ++j) {
            int row = m0 + w * 16 + q * 4 + j;
            T1[(size_t)row * 128 + col] = f2bf(tanh_f(acc[nt][j] + bav));
        }
    }
}

// ---------------- beta = softmax(T1 @ Va) ----------------
__global__ __launch_bounds__(256) void k_att2(const unsigned short* __restrict__ T1,
                                              const unsigned short* __restrict__ VaT,
                                              unsigned short* __restrict__ beta) {
    __shared__ __align__(16) char smem[52224];
    unsigned short* a_lds = (unsigned short*)smem;
    unsigned short* b_lds = (unsigned short*)(smem + 17408);
    float* lg  = (float*)smem;
    float* inv = (float*)(smem + 34048);
    int tid = threadIdx.x;
    int m0 = blockIdx.x * 64;
    stage128(T1 + (size_t)m0 * 128, a_lds, 64, tid);
    stage128(VaT, b_lds, 128, tid);
    __syncthreads();
    int w = tid >> 6, l = tid & 63, q = l >> 4, r = l & 15;
    f32x4 acc[8] = {};
    #pragma unroll
    for (int kc = 0; kc < 4; ++kc) {
        bf16x8 a = *(const bf16x8*)(a_lds + (w * 16 + r) * 136 + kc * 32 + q * 8);
        #pragma unroll
        for (int nt = 0; nt < 8; ++nt) {
            bf16x8 b = *(const bf16x8*)(b_lds + (nt * 16 + r) * 136 + kc * 32 + q * 8);
            acc[nt] = mfma16(a, b, acc[nt]);
        }
    }
    __syncthreads();
    #pragma unroll
    for (int nt = 0; nt < 8; ++nt)
        #pragma unroll
        for (int j = 0; j < 4; ++j)
            lg[(w * 16 + q * 4 + j) * 133 + nt * 16 + r] = acc[nt][j];
    __syncthreads();
    if (tid < 64) {
        float mx = -1e30f;
        for (int c = 0; c < 128; ++c) mx = fmaxf(mx, lg[tid * 133 + c]);
        float s = 0.f;
        for (int c = 0; c < 128; ++c) {
            float e = __expf(lg[tid * 133 + c] - mx);
            lg[tid * 133 + c] = e;
            s += e;
        }
        inv[tid] = 1.0f / s;
    }
    __syncthreads();
    for (int i = tid; i < 64 * 128; i += 256) {
        int rr = i >> 7, cc = i & 127;
        beta[(size_t)(m0 + rr) * 128 + cc] = f2bf(lg[rr * 133 + cc] * inv[rr]);
    }
}

// ---------------- poolT[t*512+b][d] = beta[b] @ H[b] ----------------
__global__ __launch_bounds__(256) void k_pool(const unsigned short* __restrict__ beta,
                                              const unsigned short* __restrict__ HT,
                                              unsigned short* __restrict__ poolT) {
    __shared__ unsigned short a_lds[64 * 136];
    __shared__ unsigned short b_lds[128 * 136];
    int tid = threadIdx.x;
    int b = blockIdx.x >> 1, mh = blockIdx.x & 1;
    stage128(beta + ((size_t)b * 128 + mh * 64) * 128, a_lds, 64, tid);
    stage128(HT + (size_t)b * 16384, b_lds, 128, tid);
    __syncthreads();
    int w = tid >> 6, l = tid & 63, q = l >> 4, r = l & 15;
    f32x4 acc[8] = {};
    #pragma unroll
    for (int kc = 0; kc < 4; ++kc) {
        bf16x8 a = *(const bf16x8*)(a_lds + (w * 16 + r) * 136 + kc * 32 + q * 8);
        #pragma unroll
        for (int nt = 0; nt < 8; ++nt) {
            bf16x8 bb = *(const bf16x8*)(b_lds + (nt * 16 + r) * 136 + kc * 32 + q * 8);
            acc[nt] = mfma16(a, bb, acc[nt]);
        }
    }
    #pragma unroll
    for (int nt = 0; nt < 8; ++nt)
        #pragma unroll
        for (int j = 0; j < 4; ++j) {
            int t = mh * 64 + w * 16 + q * 4 + j;
            poolT[((size_t)t * 512 + b) * 128 + nt * 16 + r] = f2bf(acc[nt][j]);
        }
}

// ---------------- Gx = pool @ W + bias, packed for k_seq v4 ----------------
// Gxp (shorts): ((((g*128+t)*4+qf)*4+c)*2+pair)*512 + l*8 + (gate&1)*4 + j
__global__ __launch_bounds__(256) void k_gx(const unsigned short* __restrict__ poolT,
                                            const unsigned short* __restrict__ WT,
                                            const float* __restrict__ bias,
                                            unsigned short* __restrict__ Gxp) {
    __shared__ unsigned short a_lds[64 * 136];
    __shared__ unsigned short b_lds[128 * 136];
    int tid = threadIdx.x;
    int mblk = blockIdx.x >> 3, nb = blockIdx.x & 7;
    int t = mblk >> 3;
    int m0 = mblk * 64, n0 = nb * 128;
    stage128(poolT + (size_t)m0 * 128, a_lds, 64, tid);
    stage128(WT + (size_t)n0 * 128, b_lds, 128, tid);
    __syncthreads();
    int w = tid >> 6, l = tid & 63, q = l >> 4, r = l & 15;
    f32x4 acc[8] = {};
    #pragma unroll
    for (int kc = 0; kc < 4; ++kc) {
        bf16x8 a = *(const bf16x8*)(a_lds + (w * 16 + r) * 136 + kc * 32 + q * 8);
        #pragma unroll
        for (int nt = 0; nt < 8; ++nt) {
            bf16x8 bb = *(const bf16x8*)(b_lds + (nt * 16 + r) * 136 + kc * 32 + q * 8);
            acc[nt] = mfma16(a, bb, acc[nt]);
        }
    }
    int g_seq = (mblk & 7) * 4 + w;   // wave's 16 rows = one sequential batch group
    #pragma unroll
    for (int nt = 0; nt < 8; ++nt) {
        int col0 = n0 + nt * 16;
        float bv = bias[col0 + r];
        int gate = col0 >> 8;
        int rem = col0 & 255;
        int qfx = rem >> 6, cx = (rem >> 4) & 3;
        int pair = gate >> 1, lo = gate & 1;
        size_t s16 = ((((size_t)g_seq * 128 + t) * 4 + qfx) * 4 + cx) * 2 + pair;
        ushort4 o;
        o.x = f2bf(acc[nt][0] + bv);
        o.y = f2bf(acc[nt][1] + bv);
        o.z = f2bf(acc[nt][2] + bv);
        o.w = f2bf(acc[nt][3] + bv);
        *(ushort4*)(Gxp + s16 * 512 + l * 8 + lo * 4) = o;
    }
}

// ---------------- sequential LSTM: 128 blocks = 32 groups x 4 quarters ----------------
// hx slot per (block, t): 1088 shorts = h quarter in A-frag order (1024 shorts)
//                         + 16 f32 y partial (32 shorts) + pad
__global__ __launch_bounds__(256, 1) void k_seq(const unsigned short* __restrict__ Gxp,
                                                const unsigned short* __restrict__ Upk,
                                                const float* __restrict__ Wy,
                                                const float* __restrict__ fcW,
                                                const float* __restrict__ fcb,
                                                const float* __restrict__ y0,
                                                unsigned short* __restrict__ hx,
                                                unsigned int* __restrict__ flags,
                                                float* __restrict__ out) {
    extern __shared__ __align__(16) char dyn[];
    unsigned short* u_lds = (unsigned short*)dyn;             // 131072 B
    unsigned short* h_own = (unsigned short*)(dyn + 131072);  // 2 x 1024 shorts
    float* ypart = (float*)(dyn + 135168);                    // [2][16][4]

    const int tid = threadIdx.x;
    const int bx = blockIdx.x;
    const int g = bx >> 2, qf = bx & 3;
    const int w = tid >> 6, l = tid & 63, q = l >> 4, r = l & 15;
    const float fcb0 = fcb[0];

    // stage this quarter's U slice (128 KB) into LDS, B-frag order
    {
        const bf16x8* src = (const bf16x8*)(Upk + (size_t)qf * 65536);
        bf16x8* dst = (bf16x8*)u_lds;
        for (int i = tid; i < 8192; i += 256) dst[i] = src[i];
    }
    const int kk = qf * 64 + w * 16 + r;   // this lane's owned h index (HS)
    float wyv[4];
    #pragma unroll
    for (int gate = 0; gate < 4; ++gate) wyv[gate] = Wy[gate * 256 + kk];
    const float fw = fcW[kk];
    float c_st[4] = {0.f, 0.f, 0.f, 0.f};

    int sib[3];
    {
        int n = 0;
        for (int s2 = 0; s2 < 4; ++s2)
            if (s2 != qf) sib[n++] = g * 4 + s2;
    }
    __syncthreads();

    float* outh = out + 512;
    const int k_l = w * 16 + r;
    const int fragoff = (((k_l >> 5) * 4 + ((k_l >> 3) & 3)) * 16) * 8 + (k_l & 7);

    for (int t = 0; t < 128; ++t) {
        const int par = t & 1, npar = par ^ 1;

        // Gx (independent of siblings) issued first
        size_t gb = ((((size_t)g * 128 + t) * 4 + qf) * 4 + w) * 2;
        const bf16x8* gq = (const bf16x8*)Gxp;
        bf16x8 gx0 = gq[gb * 64 + l];
        bf16x8 gx1 = gq[(gb + 1) * 64 + l];

        f32x4 acc[4];
        float yprev[4];
        if (t) {
            if (l == 0) {
                unsigned f0, f1, f2;
                do {
                    f0 = __hip_atomic_load(flags + sib[0], __ATOMIC_RELAXED, __HIP_MEMORY_SCOPE_AGENT);
                    f1 = __hip_atomic_load(flags + sib[1], __ATOMIC_RELAXED, __HIP_MEMORY_SCOPE_AGENT);
                    f2 = __hip_atomic_load(flags + sib[2], __ATOMIC_RELAXED, __HIP_MEMORY_SCOPE_AGENT);
                } while (f0 < (unsigned)t || f1 < (unsigned)t || f2 < (unsigned)t);
            }
            __builtin_amdgcn_fence(__ATOMIC_ACQUIRE, "agent");  // buffer_inv, no wbl2

            // gather 8 A-frags: own 2 from LDS, 6 from siblings via sc1 loads
            bf16x8 afr[8];
            #pragma unroll
            for (int kc = 0; kc < 8; ++kc) {
                int o = kc >> 1, kl = kc & 1;
                int foff = ((kl * 4 + q) * 16 + r) * 8;
                if (o == qf) {
                    afr[kc] = *(const bf16x8*)(h_own + par * 1024 + foff);
                } else {
                    int so = (o < qf) ? o : o - 1;
                    const unsigned short* ps = hx + ((size_t)sib[so] * 128 + (t - 1)) * 1088;
                    union { unsigned long long u[2]; bf16x8 v; } cvt;
                    cvt.u[0] = __hip_atomic_load((const unsigned long long*)(ps + foff),
                                                 __ATOMIC_RELAXED, __HIP_MEMORY_SCOPE_AGENT);
                    cvt.u[1] = __hip_atomic_load((const unsigned long long*)(ps + foff + 4),
                                                 __ATOMIC_RELAXED, __HIP_MEMORY_SCOPE_AGENT);
                    afr[kc] = cvt.v;
                }
            }
            // y_prev = fcb0 + own 4 wave-partials (LDS) + 3 sibling partials (L3)
            #pragma unroll
            for (int j = 0; j < 4; ++j) {
                int row = q * 4 + j;
                float s = fcb0 + ypart[(par * 16 + row) * 4 + 0] + ypart[(par * 16 + row) * 4 + 1]
                               + ypart[(par * 16 + row) * 4 + 2] + ypart[(par * 16 + row) * 4 + 3];
                #pragma unroll
                for (int s2 = 0; s2 < 3; ++s2) {
                    const float* py = (const float*)(hx + ((size_t)sib[s2] * 128 + (t - 1)) * 1088 + 1024);
                    s += __hip_atomic_load(py + row, __ATOMIC_RELAXED, __HIP_MEMORY_SCOPE_AGENT);
                }
                yprev[j] = s;
            }
            #pragma unroll
            for (int gate = 0; gate < 4; ++gate)
                #pragma unroll
                for (int j = 0; j < 4; ++j) acc[gate][j] = yprev[j] * wyv[gate];
            #pragma unroll
            for (int kc = 0; kc < 8; ++kc) {
                #pragma unroll
                for (int gate = 0; gate < 4; ++gate) {
                    bf16x8 b = *(const bf16x8*)(u_lds + ((size_t)((w * 4 + gate) * 8 + kc) * 64 + l) * 8);
                    acc[gate] = mfma16(afr[kc], b, acc[gate]);
                }
            }
        } else {
            #pragma unroll
            for (int j = 0; j < 4; ++j) yprev[j] = y0[g * 16 + q * 4 + j];
            #pragma unroll
            for (int gate = 0; gate < 4; ++gate)
                #pragma unroll
                for (int j = 0; j < 4; ++j) acc[gate][j] = yprev[j] * wyv[gate];
        }

        // ---- LSTM cell: lane owns 4 rows x 1 k ----
        unsigned short* ms = hx + ((size_t)bx * 128 + t) * 1088;
        float ypj[4];
        #pragma unroll
        for (int j = 0; j < 4; ++j) {
            int row = q * 4 + j;
            float iv = sigm(acc[0][j] + bf2f((unsigned short)gx0[j]));
            float fv = sigm(acc[1][j] + bf2f((unsigned short)gx0[4 + j]));
            float gv = tanh_f(acc[2][j] + bf2f((unsigned short)gx1[j]));
            float ov = sigm(acc[3][j] + bf2f((unsigned short)gx1[4 + j]));
            float c = fv * c_st[j] + iv * gv;
            c_st[j] = c;
            float hv = ov * tanh_f(c);
            unsigned short hb = f2bf(hv);
            outh[((size_t)(g * 16 + row) * 128 + t) * 256 + kk] = hv;     // plain store
            __hip_atomic_store(ms + fragoff + row * 8, hb,
                               __ATOMIC_RELAXED, __HIP_MEMORY_SCOPE_AGENT); // sc1, no L2 dirt
            h_own[npar * 1024 + fragoff + row * 8] = hb;
            ypj[j] = hv * fw;
        }
        #pragma unroll
        for (int j = 0; j < 4; ++j) {   // reduce over 16 r-lanes
            float v = ypj[j];
            v += __shfl_xor(v, 1);
            v += __shfl_xor(v, 2);
            v += __shfl_xor(v, 4);
            v += __shfl_xor(v, 8);
            if (r == 0) ypart[(npar * 16 + q * 4 + j) * 4 + w] = v;
        }
        __syncthreads();   // drains every wave's sc1 h stores (vmcnt(0) pre-barrier)
        if (tid < 16) {    // publish this block's y partial
            float s = ypart[(npar * 16 + tid) * 4 + 0] + ypart[(npar * 16 + tid) * 4 + 1]
                    + ypart[(npar * 16 + tid) * 4 + 2] + ypart[(npar * 16 + tid) * 4 + 3];
            __hip_atomic_store((float*)(ms + 1024) + tid, s,
                               __ATOMIC_RELAXED, __HIP_MEMORY_SCOPE_AGENT);
        }
        __builtin_amdgcn_s_waitcnt(0);   // y stores drained; orders the flag below
        if (tid == 0)
            __hip_atomic_store(flags + bx, (unsigned)(t + 1),
                               __ATOMIC_RELAXED, __HIP_MEMORY_SCOPE_AGENT);
    }

    // final y(128): block qf==0 of each group writes out
    if (qf == 0) {
        if (tid == 0) {
            unsigned f0, f1, f2;
            do {
                f0 = __hip_atomic_load(flags + sib[0], __ATOMIC_RELAXED, __HIP_MEMORY_SCOPE_AGENT);
                f1 = __hip_atomic_load(flags + sib[1], __ATOMIC_RELAXED, __HIP_MEMORY_SCOPE_AGENT);
                f2 = __hip_atomic_load(flags + sib[2], __ATOMIC_RELAXED, __HIP_MEMORY_SCOPE_AGENT);
            } while (f0 < 128u || f1 < 128u || f2 < 128u);
        }
        __syncthreads();
        __builtin_amdgcn_fence(__ATOMIC_ACQUIRE, "agent");
        if (tid < 16) {
            float s = fcb0 + ypart[tid * 4 + 0] + ypart[tid * 4 + 1]
                           + ypart[tid * 4 + 2] + ypart[tid * 4 + 3];   // npar at t=127 is 0
            #pragma unroll
            for (int s2 = 0; s2 < 3; ++s2) {
                const float* py = (const float*)(hx + ((size_t)sib[s2] * 128 + 127) * 1088 + 1024);
                s += __hip_atomic_load(py + tid, __ATOMIC_RELAXED, __HIP_MEMORY_SCOPE_AGENT);
            }
            out[g * 16 + tid] = s;
        }
    }
}

extern "C" void kernel_launch(void* const* d_in, const int* in_sizes, int n_in,
                              void* d_out, int out_size, void* d_ws, size_t ws_size,
                              hipStream_t stream) {
    const float* H    = (const float*)d_in[0];
    const float* y0   = (const float*)d_in[1];
    const float* Wa   = (const float*)d_in[2];
    // d_in[3] = Ua: multiplied by an all-zero state in the reference -> unused
    const float* ba   = (const float*)d_in[4];
    const float* Va   = (const float*)d_in[5];
    const float* W    = (const float*)d_in[6];
    const float* U    = (const float*)d_in[7];
    const float* bias = (const float*)d_in[8];
    const float* Wy   = (const float*)d_in[9];
    const float* fcW  = (const float*)d_in[10];
    const float* fcb  = (const float*)d_in[11];
    float* out = (float*)d_out;
    char* ws = (char*)d_ws;

    unsigned short* Hbf   = (unsigned short*)(ws);
    unsigned short* HT    = (unsigned short*)(ws + 16777216);
    unsigned short* T1    = (unsigned short*)(ws + 2 * 16777216);
    unsigned short* beta  = (unsigned short*)(ws + 3 * 16777216);
    unsigned short* poolT = (unsigned short*)(ws + 4 * 16777216);
    unsigned short* Gxp   = (unsigned short*)(ws + (size_t)5 * 16777216);        // 134.2 MB
    unsigned short* WaT   = (unsigned short*)(ws + (size_t)5 * 16777216 + 134217728);
    unsigned short* VaT   = WaT + 16384;
    unsigned short* WT    = VaT + 16384;
    unsigned short* Upk   = WT + 131072;
    unsigned int*   flags = (unsigned int*)(Upk + 262144);
    // hx (35.7 MB) overlays Hbf/HT/T1 -- all dead before k_seq runs
    unsigned short* hx    = (unsigned short*)ws;

    hipFuncSetAttribute((const void*)k_seq, hipFuncAttributeMaxDynamicSharedMemorySize, 135680);

    hipLaunchKernelGGL(k_prepw, dim3(1666), dim3(256), 0, stream, Wa, Va, W, U,
                       WaT, VaT, WT, Upk, flags);
    hipLaunchKernelGGL(k_preph, dim3(8192), dim3(256), 0, stream, H, Hbf, HT);
    hipLaunchKernelGGL(k_att1, dim3(1024), dim3(256), 0, stream, Hbf, WaT, ba, T1);
    hipLaunchKernelGGL(k_att2, dim3(1024), dim3(256), 0, stream, T1, VaT, beta);
    hipLaunchKernelGGL(k_pool, dim3(1024), dim3(256), 0, stream, beta, HT, poolT);
    hipLaunchKernelGGL(k_gx, dim3(8192), dim3(256), 0, stream, poolT, WT, bias, Gxp);
    hipLaunchKernelGGL(k_seq, dim3(128), dim3(256), 135680, stream, Gxp, Upk, Wy, fcW, fcb,
                       y0, hx, flags, out);
}